// Round 1
// baseline (3230.199 us; speedup 1.0000x reference)
//
#include <hip/hip_runtime.h>
#include <math.h>

#define D_MODEL 2048
#define FFN     4096
#define NE      8
#define T_TOK   2048   // 2 * 1024 tokens

#define BT 64
#define BN 64
#define BK 32

// ---------------- router: one wave per token ----------------
__global__ __launch_bounds__(256) void router_kernel(
    const float* __restrict__ x, const float* __restrict__ Wr,
    int* __restrict__ counts, int* __restrict__ token_list,
    float* __restrict__ score_list)
{
    int wid  = (blockIdx.x * blockDim.x + threadIdx.x) >> 6;  // token id
    int lane = threadIdx.x & 63;
    if (wid >= T_TOK) return;
    const float* xr = x + (size_t)wid * D_MODEL;

    float acc[NE];
#pragma unroll
    for (int e = 0; e < NE; ++e) acc[e] = 0.f;

    for (int d = lane; d < D_MODEL; d += 64) {
        float xv = xr[d];
        const float4* w = (const float4*)(Wr + (size_t)d * NE);
        float4 w0 = w[0], w1 = w[1];
        acc[0] = fmaf(xv, w0.x, acc[0]); acc[1] = fmaf(xv, w0.y, acc[1]);
        acc[2] = fmaf(xv, w0.z, acc[2]); acc[3] = fmaf(xv, w0.w, acc[3]);
        acc[4] = fmaf(xv, w1.x, acc[4]); acc[5] = fmaf(xv, w1.y, acc[5]);
        acc[6] = fmaf(xv, w1.z, acc[6]); acc[7] = fmaf(xv, w1.w, acc[7]);
    }
#pragma unroll
    for (int e = 0; e < NE; ++e) {
        float v = acc[e];
#pragma unroll
        for (int off = 32; off > 0; off >>= 1) v += __shfl_xor(v, off, 64);
        acc[e] = v;
    }
    if (lane == 0) {
        float m = acc[0];
#pragma unroll
        for (int e = 1; e < NE; ++e) m = fmaxf(m, acc[e]);
        float g[NE], s = 0.f;
#pragma unroll
        for (int e = 0; e < NE; ++e) { g[e] = expf(acc[e] - m); s += g[e]; }
        float inv = 1.f / s;
#pragma unroll
        for (int e = 0; e < NE; ++e) g[e] *= inv;
        // two SMALLEST gates (faithful: top_k(-gates)); ties -> lower index
        int i0 = 0; float g0 = g[0];
#pragma unroll
        for (int e = 1; e < NE; ++e) if (g[e] < g0) { g0 = g[e]; i0 = e; }
        int i1 = -1; float g1 = 0.f;
#pragma unroll
        for (int e = 0; e < NE; ++e) {
            if (e == i0) continue;
            if (i1 < 0 || g[e] < g1) { g1 = g[e]; i1 = e; }
        }
        float denom = g0 + g1;            // gates positive -> sum(|.|)
        float s0 = g0 / denom, s1 = g1 / denom;
        int p0 = atomicAdd(&counts[i0], 1);
        token_list[i0 * T_TOK + p0] = wid;
        score_list[i0 * T_TOK + p0] = s0;
        int p1 = atomicAdd(&counts[i1], 1);
        token_list[i1 * T_TOK + p1] = wid;
        score_list[i1 * T_TOK + p1] = s1;
    }
}

// ---------------- scan: 8-element exclusive prefix ----------------
__global__ void scan_kernel(const int* __restrict__ counts, int* __restrict__ base)
{
    if (threadIdx.x == 0) {
        int acc = 0;
        for (int e = 0; e < NE; ++e) { base[e] = acc; acc += counts[e]; }
    }
}

// ---------------- gemm1: act = silu(X@W1) * (X@V1), grouped/gathered ----------------
__global__ __launch_bounds__(256) void gemm1_kernel(
    const float* __restrict__ x, const float* __restrict__ W1,
    const float* __restrict__ V1, const int* __restrict__ counts,
    const int* __restrict__ base, const int* __restrict__ token_list,
    float* __restrict__ act)
{
    int e    = blockIdx.z;
    int cnt  = counts[e];
    int row0 = blockIdx.y * BT;
    if (row0 >= cnt) return;
    int n0   = blockIdx.x * BN;

    __shared__ float As[BK][BT + 4];
    __shared__ float B1s[BK][BN];
    __shared__ float B2s[BK][BN];
    __shared__ int   toks[BT];

    int tid = threadIdx.x;
    if (tid < BT) {
        int r = row0 + tid;
        toks[tid] = token_list[e * T_TOK + (r < cnt ? r : 0)];
    }
    __syncthreads();

    const float* W1e = W1 + (size_t)e * D_MODEL * FFN + n0;
    const float* V1e = V1 + (size_t)e * D_MODEL * FFN + n0;

    float ah[4][4] = {{0.f}}, av[4][4] = {{0.f}};
    int ty = tid >> 4, tx = tid & 15;

    for (int k0 = 0; k0 < D_MODEL; k0 += BK) {
#pragma unroll
        for (int i = 0; i < 2; ++i) {           // A: 64 rows x 32 k (512 float4)
            int idx = tid + i * 256;
            int r   = idx >> 3;                 // / (BK/4)
            int k4  = idx & 7;
            float4 a = *(const float4*)(x + (size_t)toks[r] * D_MODEL + k0 + k4 * 4);
            As[k4 * 4 + 0][r] = a.x; As[k4 * 4 + 1][r] = a.y;
            As[k4 * 4 + 2][r] = a.z; As[k4 * 4 + 3][r] = a.w;
        }
#pragma unroll
        for (int i = 0; i < 2; ++i) {           // B1/B2: 32 k x 64 n
            int idx = tid + i * 256;
            int kr  = idx >> 4;                 // / (BN/4)
            int n4  = idx & 15;
            *(float4*)&B1s[kr][n4 * 4] = *(const float4*)(W1e + (size_t)(k0 + kr) * FFN + n4 * 4);
            *(float4*)&B2s[kr][n4 * 4] = *(const float4*)(V1e + (size_t)(k0 + kr) * FFN + n4 * 4);
        }
        __syncthreads();
#pragma unroll
        for (int kk = 0; kk < BK; ++kk) {
            float4 a4  = *(float4*)&As[kk][ty * 4];
            float4 b14 = *(float4*)&B1s[kk][tx * 4];
            float4 b24 = *(float4*)&B2s[kk][tx * 4];
            float aa[4]  = {a4.x, a4.y, a4.z, a4.w};
            float bb1[4] = {b14.x, b14.y, b14.z, b14.w};
            float bb2[4] = {b24.x, b24.y, b24.z, b24.w};
#pragma unroll
            for (int i2 = 0; i2 < 4; ++i2)
#pragma unroll
                for (int j = 0; j < 4; ++j) {
                    ah[i2][j] = fmaf(aa[i2], bb1[j], ah[i2][j]);
                    av[i2][j] = fmaf(aa[i2], bb2[j], av[i2][j]);
                }
        }
        __syncthreads();
    }

    int gbase = base[e];
#pragma unroll
    for (int i2 = 0; i2 < 4; ++i2) {
        int r = row0 + ty * 4 + i2;
        if (r >= cnt) continue;
        float4 o;
        float* op = &o.x;
#pragma unroll
        for (int j = 0; j < 4; ++j) {
            float h  = ah[i2][j];
            float sv = h / (1.f + expf(-h));    // silu
            op[j] = sv * av[i2][j];
        }
        *(float4*)(act + (size_t)(gbase + r) * FFN + n0 + tx * 4) = o;
    }
}

// ---------------- gemm2: y[t] += score * (act @ W2_e), atomic scatter ----------------
__global__ __launch_bounds__(256) void gemm2_kernel(
    const float* __restrict__ act, const float* __restrict__ W2,
    const int* __restrict__ counts, const int* __restrict__ base,
    const int* __restrict__ token_list, const float* __restrict__ score_list,
    float* __restrict__ y)
{
    int e    = blockIdx.z;
    int cnt  = counts[e];
    int row0 = blockIdx.y * BT;
    if (row0 >= cnt) return;
    int n0   = blockIdx.x * BN;
    int gbase = base[e];

    __shared__ float As[BK][BT + 4];
    __shared__ float Bs[BK][BN];

    int tid = threadIdx.x;
    float acc[4][4] = {{0.f}};
    int ty = tid >> 4, tx = tid & 15;
    const float* W2e = W2 + (size_t)e * FFN * D_MODEL + n0;

    for (int k0 = 0; k0 < FFN; k0 += BK) {
#pragma unroll
        for (int i = 0; i < 2; ++i) {
            int idx = tid + i * 256;
            int r   = idx >> 3;
            int k4  = idx & 7;
            int rr  = (row0 + r < cnt) ? (row0 + r) : row0;  // clamp to valid row
            float4 a = *(const float4*)(act + (size_t)(gbase + rr) * FFN + k0 + k4 * 4);
            As[k4 * 4 + 0][r] = a.x; As[k4 * 4 + 1][r] = a.y;
            As[k4 * 4 + 2][r] = a.z; As[k4 * 4 + 3][r] = a.w;
        }
#pragma unroll
        for (int i = 0; i < 2; ++i) {
            int idx = tid + i * 256;
            int kr  = idx >> 4;
            int n4  = idx & 15;
            *(float4*)&Bs[kr][n4 * 4] = *(const float4*)(W2e + (size_t)(k0 + kr) * D_MODEL + n4 * 4);
        }
        __syncthreads();
#pragma unroll
        for (int kk = 0; kk < BK; ++kk) {
            float4 a4 = *(float4*)&As[kk][ty * 4];
            float4 b4 = *(float4*)&Bs[kk][tx * 4];
            float aa[4] = {a4.x, a4.y, a4.z, a4.w};
            float bb[4] = {b4.x, b4.y, b4.z, b4.w};
#pragma unroll
            for (int i2 = 0; i2 < 4; ++i2)
#pragma unroll
                for (int j = 0; j < 4; ++j)
                    acc[i2][j] = fmaf(aa[i2], bb[j], acc[i2][j]);
        }
        __syncthreads();
    }

#pragma unroll
    for (int i2 = 0; i2 < 4; ++i2) {
        int r = row0 + ty * 4 + i2;
        if (r >= cnt) continue;
        int   t = token_list[e * T_TOK + r];
        float s = score_list[e * T_TOK + r];
        float* yr = y + (size_t)t * D_MODEL + n0 + tx * 4;
#pragma unroll
        for (int j = 0; j < 4; ++j)
            atomicAdd(yr + j, s * acc[i2][j]);
    }
}

extern "C" void kernel_launch(void* const* d_in, const int* in_sizes, int n_in,
                              void* d_out, int out_size, void* d_ws, size_t ws_size,
                              hipStream_t stream) {
    const float* x  = (const float*)d_in[0];
    const float* Wr = (const float*)d_in[1];
    const float* W1 = (const float*)d_in[2];
    const float* V1 = (const float*)d_in[3];
    const float* W2 = (const float*)d_in[4];
    float* y = (float*)d_out;

    char* ws = (char*)d_ws;
    int*   counts     = (int*)ws;                       // 32 B
    int*   base       = (int*)(ws + 256);               // 32 B
    int*   token_list = (int*)(ws + 1024);              // 64 KB
    float* score_list = (float*)(ws + 1024 + 65536);    // 64 KB
    float* act        = (float*)(ws + 262144);          // 4096 x 4096 f32 = 64 MB

    hipMemsetAsync(counts, 0, NE * sizeof(int), stream);
    hipMemsetAsync(y, 0, (size_t)T_TOK * D_MODEL * sizeof(float), stream);

    router_kernel<<<T_TOK / 4, 256, 0, stream>>>(x, Wr, counts, token_list, score_list);
    scan_kernel<<<1, 64, 0, stream>>>(counts, base);
    gemm1_kernel<<<dim3(FFN / BN, T_TOK / BT, NE), 256, 0, stream>>>(
        x, W1, V1, counts, base, token_list, act);
    gemm2_kernel<<<dim3(D_MODEL / BN, T_TOK / BT, NE), 256, 0, stream>>>(
        act, W2, counts, base, token_list, score_list, y);
}

// Round 3
// 1433.270 us; speedup vs baseline: 2.2537x; 2.2537x over previous
//
#include <hip/hip_runtime.h>
#include <math.h>

#define D_MODEL 2048
#define FFN     4096
#define NE      8
#define T_TOK   2048   // 2 * 1024 tokens

#define BM  128
#define BN  128
#define BK  32
#define BKP 40   // LDS row pitch in shorts (80 B = 5x16B granules, bank-friendly)

typedef __attribute__((ext_vector_type(8))) short short8;
typedef __attribute__((ext_vector_type(4))) float f32x4;

#define MFMA(a, b, c) __builtin_amdgcn_mfma_f32_16x16x32_bf16((a), (b), (c), 0, 0, 0)

__device__ __forceinline__ unsigned short f2bf(float f) {
    unsigned u = __float_as_uint(f);
    u += 0x7FFFu + ((u >> 16) & 1u);          // round-to-nearest-even
    return (unsigned short)(u >> 16);
}
__device__ __forceinline__ float bf2f(unsigned short h) {
    return __uint_as_float(((unsigned)h) << 16);
}

// ---------------- router: one wave per token ----------------
__global__ __launch_bounds__(256) void router_kernel(
    const float* __restrict__ x, const float* __restrict__ Wr,
    int* __restrict__ counts, int* __restrict__ token_list,
    float* __restrict__ score_list)
{
    int wid  = (blockIdx.x * blockDim.x + threadIdx.x) >> 6;
    int lane = threadIdx.x & 63;
    if (wid >= T_TOK) return;
    const float* xr = x + (size_t)wid * D_MODEL;

    float acc[NE];
#pragma unroll
    for (int e = 0; e < NE; ++e) acc[e] = 0.f;

    for (int d = lane; d < D_MODEL; d += 64) {
        float xv = xr[d];
        const float4* w = (const float4*)(Wr + (size_t)d * NE);
        float4 w0 = w[0], w1 = w[1];
        acc[0] = fmaf(xv, w0.x, acc[0]); acc[1] = fmaf(xv, w0.y, acc[1]);
        acc[2] = fmaf(xv, w0.z, acc[2]); acc[3] = fmaf(xv, w0.w, acc[3]);
        acc[4] = fmaf(xv, w1.x, acc[4]); acc[5] = fmaf(xv, w1.y, acc[5]);
        acc[6] = fmaf(xv, w1.z, acc[6]); acc[7] = fmaf(xv, w1.w, acc[7]);
    }
#pragma unroll
    for (int e = 0; e < NE; ++e) {
        float v = acc[e];
#pragma unroll
        for (int off = 32; off > 0; off >>= 1) v += __shfl_xor(v, off, 64);
        acc[e] = v;
    }
    if (lane == 0) {
        float m = acc[0];
#pragma unroll
        for (int e = 1; e < NE; ++e) m = fmaxf(m, acc[e]);
        float g[NE], s = 0.f;
#pragma unroll
        for (int e = 0; e < NE; ++e) { g[e] = expf(acc[e] - m); s += g[e]; }
        float inv = 1.f / s;
#pragma unroll
        for (int e = 0; e < NE; ++e) g[e] *= inv;
        // two SMALLEST gates (faithful: top_k(-gates)); ties -> lower index
        int i0 = 0; float g0 = g[0];
#pragma unroll
        for (int e = 1; e < NE; ++e) if (g[e] < g0) { g0 = g[e]; i0 = e; }
        int i1 = -1; float g1 = 0.f;
#pragma unroll
        for (int e = 0; e < NE; ++e) {
            if (e == i0) continue;
            if (i1 < 0 || g[e] < g1) { g1 = g[e]; i1 = e; }
        }
        float denom = g0 + g1;
        float s0 = g0 / denom, s1 = g1 / denom;
        int p0 = atomicAdd(&counts[i0], 1);
        token_list[i0 * T_TOK + p0] = wid;
        score_list[i0 * T_TOK + p0] = s0;
        int p1 = atomicAdd(&counts[i1], 1);
        token_list[i1 * T_TOK + p1] = wid;
        score_list[i1 * T_TOK + p1] = s1;
    }
}

__global__ void scan_kernel(const int* __restrict__ counts, int* __restrict__ base)
{
    if (threadIdx.x == 0) {
        int acc = 0;
        for (int e = 0; e < NE; ++e) { base[e] = acc; acc += counts[e]; }
    }
}

// ---------------- gemm1: act = silu(X@W1) * (X@V1), bf16x3 MFMA ----------------
__global__ __launch_bounds__(256, 2) void gemm1_kernel(
    const float* __restrict__ x, const float* __restrict__ W1,
    const float* __restrict__ V1, const int* __restrict__ counts,
    const int* __restrict__ base, const int* __restrict__ token_list,
    unsigned short* __restrict__ act_h, unsigned short* __restrict__ act_l)
{
    int e    = blockIdx.z;
    int cnt  = counts[e];
    int row0 = blockIdx.y * BM;
    if (row0 >= cnt) return;
    int n0   = blockIdx.x * BN;

    __shared__ short Ah[BM][BKP], Al[BM][BKP];
    __shared__ short B1h[BN][BKP], B1l[BN][BKP];
    __shared__ short B2h[BN][BKP], B2l[BN][BKP];
    __shared__ int   toks[BM];

    int tid = threadIdx.x;
    if (tid < BM) {
        int r = row0 + tid;
        toks[tid] = token_list[e * T_TOK + (r < cnt ? r : row0)];
    }
    __syncthreads();

    int lane = tid & 63, wave = tid >> 6;
    int wm = wave >> 1, wn = wave & 1;        // 2x2 wave grid over (128,128)
    int lr = lane & 15, lq = lane >> 4;

    int ar  = tid >> 1,  akh = tid & 1;       // A staging: row, k-half
    int bn  = tid & 127, bkh = tid >> 7;      // B staging: col(n), k-half

    const float* xr  = x  + (size_t)toks[ar] * D_MODEL + 16 * akh;
    const float* W1e = W1 + (size_t)e * D_MODEL * FFN + n0 + bn;
    const float* V1e = V1 + (size_t)e * D_MODEL * FFN + n0 + bn;

    f32x4 acc1[4][4], acc2[4][4];
    f32x4 zero = {0.f, 0.f, 0.f, 0.f};
#pragma unroll
    for (int i = 0; i < 4; ++i)
#pragma unroll
        for (int j = 0; j < 4; ++j) { acc1[i][j] = zero; acc2[i][j] = zero; }

    float4 aR[4];
    float  b1R[16], b2R[16];

    auto stage_load = [&](int k0) {
#pragma unroll
        for (int i = 0; i < 4; ++i) aR[i] = *(const float4*)(xr + k0 + 4 * i);
#pragma unroll
        for (int i = 0; i < 16; ++i) {
            size_t off = (size_t)(k0 + 16 * bkh + i) * FFN;
            b1R[i] = W1e[off];
            b2R[i] = V1e[off];
        }
    };
    auto stage_write = [&]() {
        const float* af = (const float*)aR;
        short8 h0, h1, l0, l1;
#pragma unroll
        for (int i = 0; i < 8; ++i) {
            unsigned short h = f2bf(af[i]);     h0[i] = (short)h; l0[i] = (short)f2bf(af[i] - bf2f(h));
        }
#pragma unroll
        for (int i = 0; i < 8; ++i) {
            unsigned short h = f2bf(af[8 + i]); h1[i] = (short)h; l1[i] = (short)f2bf(af[8 + i] - bf2f(h));
        }
        *(short8*)&Ah[ar][16 * akh]     = h0;
        *(short8*)&Ah[ar][16 * akh + 8] = h1;
        *(short8*)&Al[ar][16 * akh]     = l0;
        *(short8*)&Al[ar][16 * akh + 8] = l1;
#pragma unroll
        for (int i = 0; i < 8; ++i) {
            unsigned short h = f2bf(b1R[i]);     h0[i] = (short)h; l0[i] = (short)f2bf(b1R[i] - bf2f(h));
        }
#pragma unroll
        for (int i = 0; i < 8; ++i) {
            unsigned short h = f2bf(b1R[8 + i]); h1[i] = (short)h; l1[i] = (short)f2bf(b1R[8 + i] - bf2f(h));
        }
        *(short8*)&B1h[bn][16 * bkh]     = h0;
        *(short8*)&B1h[bn][16 * bkh + 8] = h1;
        *(short8*)&B1l[bn][16 * bkh]     = l0;
        *(short8*)&B1l[bn][16 * bkh + 8] = l1;
#pragma unroll
        for (int i = 0; i < 8; ++i) {
            unsigned short h = f2bf(b2R[i]);     h0[i] = (short)h; l0[i] = (short)f2bf(b2R[i] - bf2f(h));
        }
#pragma unroll
        for (int i = 0; i < 8; ++i) {
            unsigned short h = f2bf(b2R[8 + i]); h1[i] = (short)h; l1[i] = (short)f2bf(b2R[8 + i] - bf2f(h));
        }
        *(short8*)&B2h[bn][16 * bkh]     = h0;
        *(short8*)&B2h[bn][16 * bkh + 8] = h1;
        *(short8*)&B2l[bn][16 * bkh]     = l0;
        *(short8*)&B2l[bn][16 * bkh + 8] = l1;
    };
    auto compute = [&]() {
        short8 fah[4], fal[4];
#pragma unroll
        for (int mt = 0; mt < 4; ++mt) {
            fah[mt] = *(short8*)&Ah[64 * wm + 16 * mt + lr][8 * lq];
            fal[mt] = *(short8*)&Al[64 * wm + 16 * mt + lr][8 * lq];
        }
#pragma unroll
        for (int nt = 0; nt < 4; ++nt) {
            int nb = 64 * wn + 16 * nt + lr;
            short8 b1h = *(short8*)&B1h[nb][8 * lq];
            short8 b1l = *(short8*)&B1l[nb][8 * lq];
            short8 b2h = *(short8*)&B2h[nb][8 * lq];
            short8 b2l = *(short8*)&B2l[nb][8 * lq];
#pragma unroll
            for (int mt = 0; mt < 4; ++mt) {
                acc1[mt][nt] = MFMA(fah[mt], b1h, acc1[mt][nt]);
                acc1[mt][nt] = MFMA(fah[mt], b1l, acc1[mt][nt]);
                acc1[mt][nt] = MFMA(fal[mt], b1h, acc1[mt][nt]);
                acc2[mt][nt] = MFMA(fah[mt], b2h, acc2[mt][nt]);
                acc2[mt][nt] = MFMA(fah[mt], b2l, acc2[mt][nt]);
                acc2[mt][nt] = MFMA(fal[mt], b2h, acc2[mt][nt]);
            }
        }
    };

    stage_load(0);
    stage_write();
    __syncthreads();
    for (int k0 = 0; k0 < D_MODEL; k0 += BK) {
        bool more = (k0 + BK) < D_MODEL;
        if (more) stage_load(k0 + BK);
        compute();
        __syncthreads();
        if (more) stage_write();
        __syncthreads();
    }

    int gbase = base[e];
#pragma unroll
    for (int mt = 0; mt < 4; ++mt) {
        int rbase = row0 + 64 * wm + 16 * mt + 4 * lq;
#pragma unroll
        for (int nt = 0; nt < 4; ++nt) {
            int col = n0 + 64 * wn + 16 * nt + lr;
            f32x4 hv = acc1[mt][nt], vv = acc2[mt][nt];
#pragma unroll
            for (int rr = 0; rr < 4; ++rr) {
                int r = rbase + rr;
                if (r < cnt) {
                    float h = hv[rr], v = vv[rr];
                    float o = (h / (1.f + expf(-h))) * v;   // silu(h)*v
                    unsigned short oh = f2bf(o);
                    size_t idx = (size_t)(gbase + r) * FFN + col;
                    act_h[idx] = oh;
                    act_l[idx] = f2bf(o - bf2f(oh));
                }
            }
        }
    }
}

// ---------------- gemm2: y[t] += score * (act @ W2_e), bf16x3 MFMA ----------------
__global__ __launch_bounds__(256, 2) void gemm2_kernel(
    const unsigned short* __restrict__ act_h, const unsigned short* __restrict__ act_l,
    const float* __restrict__ W2, const int* __restrict__ counts,
    const int* __restrict__ base, const int* __restrict__ token_list,
    const float* __restrict__ score_list, float* __restrict__ y)
{
    int e    = blockIdx.z;
    int cnt  = counts[e];
    int row0 = blockIdx.y * BM;
    if (row0 >= cnt) return;
    int n0   = blockIdx.x * BN;     // over D_MODEL
    int gbase = base[e];

    __shared__ short Ah[BM][BKP], Al[BM][BKP];
    __shared__ short Bh[BN][BKP], Bl[BN][BKP];
    __shared__ int   stok[BM];
    __shared__ float ssc[BM];

    int tid = threadIdx.x;
    if (tid < BM) {
        int r = row0 + tid;
        stok[tid] = (r < cnt) ? token_list[e * T_TOK + r] : 0;
        ssc[tid]  = (r < cnt) ? score_list[e * T_TOK + r] : 0.f;
    }
    __syncthreads();

    int lane = tid & 63, wave = tid >> 6;
    int wm = wave >> 1, wn = wave & 1;
    int lr = lane & 15, lq = lane >> 4;

    int ar  = tid >> 1,  akh = tid & 1;
    int bn  = tid & 127, bkh = tid >> 7;

    int arow = row0 + ar; if (arow >= cnt) arow = row0;
    const unsigned short* ahp = act_h + (size_t)(gbase + arow) * FFN + 16 * akh;
    const unsigned short* alp = act_l + (size_t)(gbase + arow) * FFN + 16 * akh;
    const float* W2e = W2 + (size_t)e * FFN * D_MODEL + n0 + bn;

    f32x4 acc[4][4];
    f32x4 zero = {0.f, 0.f, 0.f, 0.f};
#pragma unroll
    for (int i = 0; i < 4; ++i)
#pragma unroll
        for (int j = 0; j < 4; ++j) acc[i][j] = zero;

    short8 aRh0, aRh1, aRl0, aRl1;
    float  bR[16];

    auto stage_load = [&](int k0) {
        aRh0 = *(const short8*)(ahp + k0);
        aRh1 = *(const short8*)(ahp + k0 + 8);
        aRl0 = *(const short8*)(alp + k0);
        aRl1 = *(const short8*)(alp + k0 + 8);
#pragma unroll
        for (int i = 0; i < 16; ++i)
            bR[i] = W2e[(size_t)(k0 + 16 * bkh + i) * D_MODEL];
    };
    auto stage_write = [&]() {
        *(short8*)&Ah[ar][16 * akh]     = aRh0;
        *(short8*)&Ah[ar][16 * akh + 8] = aRh1;
        *(short8*)&Al[ar][16 * akh]     = aRl0;
        *(short8*)&Al[ar][16 * akh + 8] = aRl1;
        short8 h0, h1, l0, l1;
#pragma unroll
        for (int i = 0; i < 8; ++i) {
            unsigned short h = f2bf(bR[i]);     h0[i] = (short)h; l0[i] = (short)f2bf(bR[i] - bf2f(h));
        }
#pragma unroll
        for (int i = 0; i < 8; ++i) {
            unsigned short h = f2bf(bR[8 + i]); h1[i] = (short)h; l1[i] = (short)f2bf(bR[8 + i] - bf2f(h));
        }
        *(short8*)&Bh[bn][16 * bkh]     = h0;
        *(short8*)&Bh[bn][16 * bkh + 8] = h1;
        *(short8*)&Bl[bn][16 * bkh]     = l0;
        *(short8*)&Bl[bn][16 * bkh + 8] = l1;
    };
    auto compute = [&]() {
        short8 fah[4], fal[4];
#pragma unroll
        for (int mt = 0; mt < 4; ++mt) {
            fah[mt] = *(short8*)&Ah[64 * wm + 16 * mt + lr][8 * lq];
            fal[mt] = *(short8*)&Al[64 * wm + 16 * mt + lr][8 * lq];
        }
#pragma unroll
        for (int nt = 0; nt < 4; ++nt) {
            int nb = 64 * wn + 16 * nt + lr;
            short8 bh = *(short8*)&Bh[nb][8 * lq];
            short8 bl = *(short8*)&Bl[nb][8 * lq];
#pragma unroll
            for (int mt = 0; mt < 4; ++mt) {
                acc[mt][nt] = MFMA(fah[mt], bh, acc[mt][nt]);
                acc[mt][nt] = MFMA(fah[mt], bl, acc[mt][nt]);
                acc[mt][nt] = MFMA(fal[mt], bh, acc[mt][nt]);
            }
        }
    };

    stage_load(0);
    stage_write();
    __syncthreads();
    for (int k0 = 0; k0 < FFN; k0 += BK) {
        bool more = (k0 + BK) < FFN;
        if (more) stage_load(k0 + BK);
        compute();
        __syncthreads();
        if (more) stage_write();
        __syncthreads();
    }

#pragma unroll
    for (int mt = 0; mt < 4; ++mt) {
        int lrow = 64 * wm + 16 * mt + 4 * lq;
#pragma unroll
        for (int nt = 0; nt < 4; ++nt) {
            int col = n0 + 64 * wn + 16 * nt + lr;
#pragma unroll
            for (int rr = 0; rr < 4; ++rr) {
                int r = row0 + lrow + rr;
                if (r < cnt) {
                    float s = ssc[lrow + rr];
                    int   t = stok[lrow + rr];
                    atomicAdd(&y[(size_t)t * D_MODEL + col], s * acc[mt][nt][rr]);
                }
            }
        }
    }
}

extern "C" void kernel_launch(void* const* d_in, const int* in_sizes, int n_in,
                              void* d_out, int out_size, void* d_ws, size_t ws_size,
                              hipStream_t stream) {
    const float* x  = (const float*)d_in[0];
    const float* Wr = (const float*)d_in[1];
    const float* W1 = (const float*)d_in[2];
    const float* V1 = (const float*)d_in[3];
    const float* W2 = (const float*)d_in[4];
    float* y = (float*)d_out;

    char* ws = (char*)d_ws;
    int*   counts     = (int*)ws;                        // 32 B
    int*   base       = (int*)(ws + 256);                // 32 B
    int*   token_list = (int*)(ws + 1024);               // 64 KB
    float* score_list = (float*)(ws + 1024 + 65536);     // 64 KB
    unsigned short* act_h = (unsigned short*)(ws + 262144);              // 32 MB
    unsigned short* act_l = (unsigned short*)(ws + 262144 + 33554432);   // 32 MB

    hipMemsetAsync(counts, 0, NE * sizeof(int), stream);
    hipMemsetAsync(y, 0, (size_t)T_TOK * D_MODEL * sizeof(float), stream);

    router_kernel<<<T_TOK / 4, 256, 0, stream>>>(x, Wr, counts, token_list, score_list);
    scan_kernel<<<1, 64, 0, stream>>>(counts, base);
    gemm1_kernel<<<dim3(FFN / BN, T_TOK / BM, NE), 256, 0, stream>>>(
        x, W1, V1, counts, base, token_list, act_h, act_l);
    gemm2_kernel<<<dim3(D_MODEL / BN, T_TOK / BM, NE), 256, 0, stream>>>(
        act_h, act_l, W2, counts, base, token_list, score_list, y);
}